// Round 8
// baseline (2208.367 us; speedup 1.0000x reference)
//
#include <hip/hip_runtime.h>

// approxmatch EMD (Fan et al.) on MI355X, B=4, N=M=4096, layout (B,3,N).
// Round 8: mega-kernel with SOFTWARE grid barrier (device-scope atomics) on a
// normal launch — R7's hipLaunchCooperativeKernel failed at dispatch (exact-
// occupancy request, no margin). Here: 512 blocks x 256 thr, launch_bounds
// (256,4) -> 4 blocks/CU capacity vs 2 required (2x co-residency margin).
// Each block covers 2 row-groups (32 rows) per phase. 20 barriers replace 30
// kernel boundaries. Math identical to validated R6 kernels: packed v2f
// (v_pk_*), exp-chaining e_t = (e_{t+1})^4 (levels exact powers of 4),
// pass3(t)+pass1(t+1) fused, level-0 sweep specialcased.

#define NPTS 4096
#define BATCH 4
#define EMD_EPS 1e-9f
#define TILE 1024        // columns staged per LDS stage
#define RPW 4            // rows per wave, in registers
#define THREADS 256      // 4 waves
#define RPB 16           // rows per wave-group pass = 4 waves * RPW
#define GRID_BLKS 512    // 128 blocks per batch; each covers 2*RPB = 32 rows

typedef float v2f __attribute__((ext_vector_type(2)));

__device__ __forceinline__ float fexp2(float x) {
#if __has_builtin(__builtin_amdgcn_exp2f)
    return __builtin_amdgcn_exp2f(x);
#else
    return exp2f(x);
#endif
}
__device__ __forceinline__ float fsqrt(float x) {
#if __has_builtin(__builtin_amdgcn_sqrtf)
    return __builtin_amdgcn_sqrtf(x);
#else
    return __sqrtf(x);
#endif
}

__device__ __forceinline__ float wave_reduce(float v) {
    v += __shfl_xor(v, 32);
    v += __shfl_xor(v, 16);
    v += __shfl_xor(v, 8);
    v += __shfl_xor(v, 4);
    v += __shfl_xor(v, 2);
    v += __shfl_xor(v, 1);
    return v;
}

// ---------------------------------------------------------------- software grid barrier
// Slot k: cnt at u[k*32], flag at u[k*32+16] (separate 64B lines). Slots are
// zeroed by hipMemsetAsync before launch (d_ws is re-poisoned every replay).
__device__ __forceinline__ void grid_barrier(unsigned* bar, int k) {
    __syncthreads();
    if (threadIdx.x == 0) {
        __threadfence();
        unsigned* cnt = bar + k * 32;
        unsigned* flg = bar + k * 32 + 16;
        unsigned old = __hip_atomic_fetch_add(cnt, 1u, __ATOMIC_ACQ_REL,
                                              __HIP_MEMORY_SCOPE_AGENT);
        if (old == GRID_BLKS - 1) {
            __hip_atomic_store(flg, 1u, __ATOMIC_RELEASE, __HIP_MEMORY_SCOPE_AGENT);
        } else {
            while (__hip_atomic_load(flg, __ATOMIC_ACQUIRE,
                                     __HIP_MEMORY_SCOPE_AGENT) == 0u)
                __builtin_amdgcn_s_sleep(1);
        }
        __threadfence();
    }
    __syncthreads();
}

// ---------------------------------------------------------------- phase: row pass, sweep 0
// remainR == 1 -> ratioL = 1/(eps + sum exp2(ls2*d)); inits remainL/remainR.
__device__ __forceinline__ void phase_rowL0(
        const float* __restrict__ x1, const float* __restrict__ x2,
        float* __restrict__ rl_b, float* __restrict__ mL_b, float* __restrict__ mR_b,
        float4* sA, float2* sZ, int row0, int lane, int tid, float ls2) {
    const float2* x2x = (const float2*)(x2);
    const float2* x2y = (const float2*)(x2 + NPTS);
    const float2* x2z = (const float2*)(x2 + 2 * NPTS);
    float px[RPW], py[RPW], pz[RPW];
    v2f acc[RPW];
#pragma unroll
    for (int r = 0; r < RPW; ++r) {
        px[r] = x1[row0 + r];
        py[r] = x1[NPTS + row0 + r];
        pz[r] = x1[2 * NPTS + row0 + r];
        acc[r] = (v2f)(0.0f);
    }
    for (int c0 = 0; c0 < NPTS; c0 += TILE) {
        __syncthreads();
        for (int i = tid; i < TILE / 2; i += THREADS) {
            int e = c0 / 2 + i;
            float2 xx = x2x[e], yy = x2y[e];
            sA[i] = make_float4(xx.x, xx.y, yy.x, yy.y);
            sZ[i] = x2z[e];
        }
        __syncthreads();
#pragma unroll 2
        for (int j = 0; j < TILE / 128; ++j) {
            float4 a = sA[lane + 64 * j];
            float2 z = sZ[lane + 64 * j];
            v2f ax = {a.x, a.y}, ay = {a.z, a.w}, az = {z.x, z.y};
#pragma unroll
            for (int r = 0; r < RPW; ++r) {
                v2f dx = px[r] - ax, dy = py[r] - ay, dz = pz[r] - az;
                v2f d = dx * dx + dy * dy + dz * dz;
                v2f sd = ls2 * d;
                v2f e2 = {fexp2(sd.x), fexp2(sd.y)};
                acc[r] += e2;
            }
        }
    }
#pragma unroll
    for (int r = 0; r < RPW; ++r) {
        float s = wave_reduce(acc[r].x + acc[r].y);
        if (lane == 0) {
            rl_b[row0 + r] = 1.0f / (EMD_EPS + s);
            mL_b[row0 + r] = 1.0f;
            mR_b[row0 + r] = 1.0f;
        }
    }
}

// ---------------------------------------------------------------- phase: col pass
__device__ __forceinline__ void phase_col(
        const float* __restrict__ x1, const float* __restrict__ x2,
        const float* __restrict__ rl_b, float* __restrict__ rr_b,
        float* __restrict__ mR_b,
        float4* sA, float4* sB, int col0, int lane, int tid, float ls2) {
    const float2* x1x = (const float2*)(x1);
    const float2* x1y = (const float2*)(x1 + NPTS);
    const float2* x1z = (const float2*)(x1 + 2 * NPTS);
    const float2* wLv = (const float2*)(rl_b);
    float px[RPW], py[RPW], pz[RPW];
    v2f acc[RPW];
#pragma unroll
    for (int r = 0; r < RPW; ++r) {
        px[r] = x2[col0 + r];
        py[r] = x2[NPTS + col0 + r];
        pz[r] = x2[2 * NPTS + col0 + r];
        acc[r] = (v2f)(0.0f);
    }
    for (int c0 = 0; c0 < NPTS; c0 += TILE) {
        __syncthreads();
        for (int i = tid; i < TILE / 2; i += THREADS) {
            int e = c0 / 2 + i;
            float2 xx = x1x[e], yy = x1y[e], zz = x1z[e], ww = wLv[e];
            sA[i] = make_float4(xx.x, xx.y, yy.x, yy.y);
            sB[i] = make_float4(zz.x, zz.y, ww.x, ww.y);
        }
        __syncthreads();
#pragma unroll 2
        for (int j = 0; j < TILE / 128; ++j) {
            float4 a = sA[lane + 64 * j];
            float4 bq = sB[lane + 64 * j];
            v2f ax = {a.x, a.y}, ay = {a.z, a.w};
            v2f az = {bq.x, bq.y}, aw = {bq.z, bq.w};
#pragma unroll
            for (int r = 0; r < RPW; ++r) {
                v2f dx = px[r] - ax, dy = py[r] - ay, dz = pz[r] - az;
                v2f d = dx * dx + dy * dy + dz * dz;
                v2f sd = ls2 * d;
                v2f e2 = {fexp2(sd.x), fexp2(sd.y)};
                acc[r] += e2 * aw;
            }
        }
    }
#pragma unroll
    for (int r = 0; r < RPW; ++r) {
        float s = wave_reduce(acc[r].x + acc[r].y);
        if (lane == 0) {
            float rv = mR_b[col0 + r];
            float sumr = rv * s;
            float cons = fminf(rv / (sumr + EMD_EPS), 1.0f);
            rr_b[col0 + r] = cons * rv;
            mR_b[col0 + r] = fmaxf(0.0f, rv - sumr);
        }
    }
}

// ---------------------------------------------------------------- phase: row pass t (+pass1 t+1)
template <bool SQ>
__device__ __forceinline__ void phase_row(
        const float* __restrict__ x1, const float* __restrict__ x2,
        float* __restrict__ rl_b, const float* __restrict__ rr_b,
        float* __restrict__ mL_b, const float* __restrict__ mR_b,
        float* __restrict__ S_L,
        float4* sA, float4* sB, float2* sC,
        int b, int row0, int lane, int tid, float ls2, float ls2n,
        float& wcost, bool addSL) {
    const float2* x2x = (const float2*)(x2);
    const float2* x2y = (const float2*)(x2 + NPTS);
    const float2* x2z = (const float2*)(x2 + 2 * NPTS);
    const float2* wRv = (const float2*)(rr_b);
    const float2* w2v = (const float2*)(mR_b);
    float px[RPW], py[RPW], pz[RPW];
    v2f acc_a[RPW], acc_c[RPW], acc_s[RPW];
#pragma unroll
    for (int r = 0; r < RPW; ++r) {
        px[r] = x1[row0 + r];
        py[r] = x1[NPTS + row0 + r];
        pz[r] = x1[2 * NPTS + row0 + r];
        acc_a[r] = (v2f)(0.0f);
        acc_c[r] = (v2f)(0.0f);
        acc_s[r] = (v2f)(0.0f);
    }
    for (int c0 = 0; c0 < NPTS; c0 += TILE) {
        __syncthreads();
        for (int i = tid; i < TILE / 2; i += THREADS) {
            int e = c0 / 2 + i;
            float2 xx = x2x[e], yy = x2y[e], zz = x2z[e], wr = wRv[e];
            sA[i] = make_float4(xx.x, xx.y, yy.x, yy.y);
            sB[i] = make_float4(zz.x, zz.y, wr.x, wr.y);
            sC[i] = w2v[e];
        }
        __syncthreads();
#pragma unroll 2
        for (int j = 0; j < TILE / 128; ++j) {
            float4 a = sA[lane + 64 * j];
            float4 bq = sB[lane + 64 * j];
            float2 c = sC[lane + 64 * j];
            v2f ax = {a.x, a.y}, ay = {a.z, a.w};
            v2f az = {bq.x, bq.y}, wr = {bq.z, bq.w};
            v2f cw = {c.x, c.y};
#pragma unroll
            for (int r = 0; r < RPW; ++r) {
                v2f dx = px[r] - ax, dy = py[r] - ay, dz = pz[r] - az;
                v2f d = dx * dx + dy * dy + dz * dz;
                v2f er;
                if (SQ) {
                    v2f sd = ls2n * d;
                    v2f e2 = {fexp2(sd.x), fexp2(sd.y)};
                    acc_s[r] += e2 * cw;
                    v2f e4 = e2 * e2;
                    er = (e4 * e4) * wr;
                } else {
                    v2f sd = ls2 * d;
                    v2f e1 = {fexp2(sd.x), fexp2(sd.y)};
                    er = e1 * wr;
                    acc_s[r] += cw;   // e2 == 1 when next level == 0
                }
                acc_a[r] += er;
                v2f sq = {fsqrt(d.x), fsqrt(d.y)};
                acc_c[r] += er * sq;
            }
        }
    }
#pragma unroll
    for (int r = 0; r < RPW; ++r) {
        float sa = wave_reduce(acc_a[r].x + acc_a[r].y);
        float sc = wave_reduce(acc_c[r].x + acc_c[r].y);
        float ss = wave_reduce(acc_s[r].x + acc_s[r].y);
        if (lane == 0) {
            float rl = rl_b[row0 + r];
            float rem = fmaxf(0.0f, mL_b[row0 + r] - rl * sa);
            mL_b[row0 + r] = rem;
            float nrl = rem / (EMD_EPS + ss);   // next sweep's ratioL
            rl_b[row0 + r] = nrl;
            if (addSL) atomicAdd(&S_L[b], nrl);
            wcost = fmaf(rl, sc, wcost);
        }
    }
}

// ---------------------------------------------------------------- phase: level-0 cost
__device__ __forceinline__ void phase_cost_l0(
        const float* __restrict__ x1, const float* __restrict__ x2,
        const float* __restrict__ rl_b, const float* __restrict__ mR_b,
        const float* __restrict__ S_L,
        float4* sA, float4* sB, int b, int row0, int lane, int tid,
        float& wcost) {
    const float sL = S_L[b];
    const float2* x2x = (const float2*)(x2);
    const float2* x2y = (const float2*)(x2 + NPTS);
    const float2* x2z = (const float2*)(x2 + 2 * NPTS);
    const float2* wRv = (const float2*)(mR_b);
    float px[RPW], py[RPW], pz[RPW];
    v2f acc_c[RPW];
#pragma unroll
    for (int r = 0; r < RPW; ++r) {
        px[r] = x1[row0 + r];
        py[r] = x1[NPTS + row0 + r];
        pz[r] = x1[2 * NPTS + row0 + r];
        acc_c[r] = (v2f)(0.0f);
    }
    for (int c0 = 0; c0 < NPTS; c0 += TILE) {
        __syncthreads();
        for (int i = tid; i < TILE / 2; i += THREADS) {
            int e = c0 / 2 + i;
            float2 xx = x2x[e], yy = x2y[e], zz = x2z[e], rv = wRv[e];
            float wr0 = fminf(rv.x / (rv.x * sL + EMD_EPS), 1.0f) * rv.x;
            float wr1 = fminf(rv.y / (rv.y * sL + EMD_EPS), 1.0f) * rv.y;
            sA[i] = make_float4(xx.x, xx.y, yy.x, yy.y);
            sB[i] = make_float4(zz.x, zz.y, wr0, wr1);
        }
        __syncthreads();
#pragma unroll 2
        for (int j = 0; j < TILE / 128; ++j) {
            float4 a = sA[lane + 64 * j];
            float4 bq = sB[lane + 64 * j];
            v2f ax = {a.x, a.y}, ay = {a.z, a.w};
            v2f az = {bq.x, bq.y}, wr = {bq.z, bq.w};
#pragma unroll
            for (int r = 0; r < RPW; ++r) {
                v2f dx = px[r] - ax, dy = py[r] - ay, dz = pz[r] - az;
                v2f d = dx * dx + dy * dy + dz * dz;
                v2f sq = {fsqrt(d.x), fsqrt(d.y)};
                acc_c[r] += wr * sq;
            }
        }
    }
#pragma unroll
    for (int r = 0; r < RPW; ++r) {
        float sc = wave_reduce(acc_c[r].x + acc_c[r].y);
        if (lane == 0) wcost = fmaf(rl_b[row0 + r], sc, wcost);
    }
}

// ---------------------------------------------------------------- mega kernel
__global__ __launch_bounds__(THREADS, 4) void k_mega(
        const float* __restrict__ xyz1, const float* __restrict__ xyz2,
        float* __restrict__ remainL, float* __restrict__ remainR,
        float* __restrict__ ratioL, float* __restrict__ ratioR,
        unsigned* __restrict__ bar, float* __restrict__ S_L,
        float* __restrict__ cost_total, float* __restrict__ out) {
    const int tid = threadIdx.x;
    const int wave = tid >> 6, lane = tid & 63;
    const int wi = blockIdx.x;            // 0..511
    const int b = wi >> 7;                // 128 blocks per batch
    const int rb = wi & 127;              // covers rows rb*32 .. rb*32+31
    const int rbase = rb * 2 * RPB + wave * RPW;

    const float* x1 = xyz1 + b * 3 * NPTS;
    const float* x2 = xyz2 + b * 3 * NPTS;
    float* rl_b = ratioL + b * NPTS;
    float* rr_b = ratioR + b * NPTS;
    float* mL_b = remainL + b * NPTS;
    float* mR_b = remainR + b * NPTS;

    __shared__ float smem[5124];          // 20.5 KB
    float4* sA = (float4*)smem;           // 512 float4
    float4* sB = (float4*)(smem + 2048);  // 512 float4
    float2* sC = (float2*)(smem + 4096);  // 512 float2
    float*  s_cost = smem + 5120;         // 4

    int bk = 0;
    const float LOG2E = 1.4426950408889634f;
    float lv = -16384.0f;                 // level -(4^7), scaled by exact 0.25x

    // ---- sweep-0 row pass (remainR == 1); also inits remainL/remainR
#pragma unroll 1
    for (int g = 0; g < 2; ++g)
        phase_rowL0(x1, x2, rl_b, mL_b, mR_b, sA, sC, rbase + g * RPB,
                    lane, tid, lv * LOG2E);
    grid_barrier(bar, bk++);

    float wcost = 0.0f;
    for (int t = 0; t < 9; ++t) {
        float ls2 = lv * LOG2E;
#pragma unroll 1
        for (int g = 0; g < 2; ++g)
            phase_col(x1, x2, rl_b, rr_b, mR_b, sA, sB, rbase + g * RPB,
                      lane, tid, ls2);
        grid_barrier(bar, bk++);
        if (t < 8) {
            float ls2n = 0.25f * ls2;     // exact; next level is 4x smaller
#pragma unroll 1
            for (int g = 0; g < 2; ++g)
                phase_row<true>(x1, x2, rl_b, rr_b, mL_b, mR_b, S_L, sA, sB, sC,
                                b, rbase + g * RPB, lane, tid, ls2, ls2n,
                                wcost, false);
        } else {
#pragma unroll 1
            for (int g = 0; g < 2; ++g)
                phase_row<false>(x1, x2, rl_b, rr_b, mL_b, mR_b, S_L, sA, sB, sC,
                                 b, rbase + g * RPB, lane, tid, ls2, 0.0f,
                                 wcost, true);
        }
        grid_barrier(bar, bk++);
        lv *= 0.25f;
    }

    // ---- sweep 9 (level == 0) cost pass; ratioR inline from remainR & S_L
#pragma unroll 1
    for (int g = 0; g < 2; ++g)
        phase_cost_l0(x1, x2, rl_b, mR_b, S_L, sA, sB, b, rbase + g * RPB,
                      lane, tid, wcost);

    if (lane == 0) s_cost[wave] = wcost;
    __syncthreads();
    if (tid == 0)
        atomicAdd(cost_total, s_cost[0] + s_cost[1] + s_cost[2] + s_cost[3]);
    grid_barrier(bar, bk++);
    if (wi == 0 && tid == 0)
        out[0] = cost_total[0] / ((float)NPTS * (float)BATCH);
}

extern "C" void kernel_launch(void* const* d_in, const int* in_sizes, int n_in,
                              void* d_out, int out_size, void* d_ws, size_t ws_size,
                              hipStream_t stream) {
    const float* xyz1 = (const float*)d_in[0];
    const float* xyz2 = (const float*)d_in[1];
    float* out = (float*)d_out;

    const int BN = BATCH * NPTS;
    // layout: [0, 4KB): barrier slots (32 x {cnt,flag} on separate 64B lines)
    //         [4KB, 8KB): S_L[4], cost_total[1]  (zeroed with barrier area)
    //         [8KB, ...): remainL/remainR/ratioL/ratioR (BN floats each)
    unsigned* bar = (unsigned*)d_ws;
    float* misc = (float*)d_ws + 1024;
    float* S_L = misc;                    // 4
    float* cost_total = misc + 4;         // 1
    float* arrs = (float*)d_ws + 2048;
    float* remainL = arrs;
    float* remainR = arrs + 1 * BN;
    float* ratioL  = arrs + 2 * BN;
    float* ratioR  = arrs + 3 * BN;

    hipMemsetAsync(d_ws, 0, 8192, stream);   // zero barriers + S_L + cost
    k_mega<<<dim3(GRID_BLKS), dim3(THREADS), 0, stream>>>(
        xyz1, xyz2, remainL, remainR, ratioL, ratioR, bar, S_L, cost_total, out);
}